// Round 10
// baseline (5772.966 us; speedup 1.0000x reference)
//
#include <hip/hip_runtime.h>
#include <math.h>

// RNN: L=512, B=128, D=512, H=1024, fp32 in/out.
//   xproj = x @ Wx^T + bx -> d_out;  h_t = tanh(xp_t + h_{t-1} @ Wh^T) in place.
// Precision: split-bf16 (hi+lo), 3 MFMAs per product => ~fp32 accuracy.
// Round 10: DUAL-CHAIN INTERLEAVE on proven agent-scope (sc0sc1) semantics.
// R9's sc0-only fast path is REFUTED (gates timed out; 44s of bounded escapes).
// R8's 5.9us/step = ~3 serial L3-class hops; hops are irreducible, so hide
// them: each WG runs TWO independent row-group chains (mb=2p and 2p+1, same
// nb -> Wh registers shared). While chain A's flag/store latency propagates,
// the WG computes chain B, and vice versa. Flag publication is deferred into
// the next segment's gate poll, whose vmcnt(0) doubles as the store drain —
// removing the drain hop from the serial path.

#define L_SEQ 512
#define B_SZ  128
#define H_SZ  1024
#define BH    (B_SZ * H_SZ)   // 131072

typedef __bf16 bf16x8 __attribute__((ext_vector_type(8)));
typedef float  f32x4  __attribute__((ext_vector_type(4)));
typedef unsigned int uint;

union V8 { bf16x8 b; unsigned short u[8]; };

__device__ __forceinline__ unsigned short f2bf(float f) {
  unsigned int u = __float_as_uint(f);
  u += 0x7FFFu + ((u >> 16) & 1u);   // round-to-nearest-even
  return (unsigned short)(u >> 16);
}
__device__ __forceinline__ float bf2f(unsigned short s) {
  return __uint_as_float(((unsigned int)s) << 16);
}

// tanh(x) = 1 - 2/(e^{2x}+1); v_exp_f32(2^x) + v_rcp_f32. Saturates right.
__device__ __forceinline__ float fast_tanh(float x) {
  float e;
  asm("v_exp_f32 %0, %1" : "=v"(e) : "v"(x * 2.885390081777927f));
  float r;
  asm("v_rcp_f32 %0, %1" : "=v"(r) : "v"(e + 1.0f));
  return 1.0f - 2.0f * r;
}

// Agent-scope (sc0 sc1) ops: bypass L1+L2, coherent at L3 point. PROVEN (R8).
__device__ __forceinline__ void ldg16_sc(bf16x8& d, const unsigned short* p) {
  asm volatile("global_load_dwordx4 %0, %1, off sc0 sc1"
               : "=v"(d) : "v"(p) : "memory");
}
__device__ __forceinline__ uint ld4w_sc(const uint* p) {  // load + drain
  uint f;
  asm volatile("global_load_dword %0, %1, off sc0 sc1\n\ts_waitcnt vmcnt(0)"
               : "=v"(f) : "v"(p) : "memory");
  return f;
}
__device__ __forceinline__ void stg2_sc(unsigned short* p, uint v) {
  asm volatile("global_store_short %0, %1, off sc0 sc1"
               :: "v"(p), "v"(v) : "memory");
}
__device__ __forceinline__ void stg4_sc(uint* p, uint v) {
  asm volatile("global_store_dword %0, %1, off sc0 sc1"
               :: "v"(p), "v"(v) : "memory");
}

// ---- d_ws layout (ushort elements unless noted) ----
#define WS_WHH 0            // [1024][1024]
#define WS_WHL 1048576      // [1024][1024]
#define WS_WXH 2097152      // [1024][512]
#define WS_WXL 2621440      // [1024][512]
#define WS_HB  3145728      // [2 parity][2 hi/lo][BH] ushort
#define WS_CNT 3670016      // flags [4 mb][64 nb] u32

// Split fp32 weights into bf16 hi + lo(residual); zero flags.
__global__ void split_kernel(const float* __restrict__ Wh,
                             const float* __restrict__ Wx,
                             unsigned short* __restrict__ ws,
                             unsigned int* __restrict__ flags) {
  if (blockIdx.x == 0) {
    for (int i = threadIdx.x; i < 512; i += 256) flags[i] = 0u;
  }
  const int total = 1048576 + 524288;
  for (int i = blockIdx.x * blockDim.x + threadIdx.x; i < total;
       i += gridDim.x * blockDim.x) {
    const float* src; unsigned short *dh, *dl; int j;
    if (i < 1048576) { src = Wh; dh = ws + WS_WHH; dl = ws + WS_WHL; j = i; }
    else             { src = Wx; dh = ws + WS_WXH; dl = ws + WS_WXL; j = i - 1048576; }
    float v = src[j];
    unsigned short h = f2bf(v);
    dh[j] = h;
    dl[j] = f2bf(v - bf2f(h));
  }
}

// xproj: out[m][n] = sum_d x[m][d]*Wx[n][d] + bx[n]  (unchanged)
__global__ __launch_bounds__(256) void xproj_kernel(
    const float* __restrict__ x,             // [65536][512]
    const unsigned short* __restrict__ wxh,  // [1024][512]
    const unsigned short* __restrict__ wxl,
    const float* __restrict__ bx,            // [1024]
    float* __restrict__ out)                 // [65536][1024]
{
  const int bid = blockIdx.x;
  const int bn = bid & 15;
  const int bm = bid >> 4;
  const int tid = threadIdx.x;
  const int w = tid >> 6, l = tid & 63;
  const int wm = w & 1, wn = w >> 1;
  const int lr = l & 15, lk = (l >> 4) * 8;
  const int mbase = bm * 128 + wm * 64;
  const int nbase = bn * 64 + wn * 32;

  f32x4 acc[4][2] = {};

  for (int k0 = 0; k0 < 512; k0 += 32) {
    bf16x8 ah[4], al[4], bh[2], bl[2];
#pragma unroll
    for (int i = 0; i < 4; ++i) {
      const float* ap = x + (size_t)(mbase + i * 16 + lr) * 512 + k0 + lk;
      float4 v0 = *reinterpret_cast<const float4*>(ap);
      float4 v1 = *reinterpret_cast<const float4*>(ap + 4);
      float vv[8] = {v0.x, v0.y, v0.z, v0.w, v1.x, v1.y, v1.z, v1.w};
      V8 hh, ll;
#pragma unroll
      for (int e = 0; e < 8; ++e) {
        unsigned short hb = f2bf(vv[e]);
        hh.u[e] = hb;
        ll.u[e] = f2bf(vv[e] - bf2f(hb));
      }
      ah[i] = hh.b; al[i] = ll.b;
    }
#pragma unroll
    for (int j = 0; j < 2; ++j) {
      size_t boff = (size_t)(nbase + j * 16 + lr) * 512 + k0 + lk;
      bh[j] = *reinterpret_cast<const bf16x8*>(wxh + boff);
      bl[j] = *reinterpret_cast<const bf16x8*>(wxl + boff);
    }
#pragma unroll
    for (int i = 0; i < 4; ++i)
#pragma unroll
      for (int j = 0; j < 2; ++j) {
        acc[i][j] = __builtin_amdgcn_mfma_f32_16x16x32_bf16(ah[i], bh[j], acc[i][j], 0, 0, 0);
        acc[i][j] = __builtin_amdgcn_mfma_f32_16x16x32_bf16(ah[i], bl[j], acc[i][j], 0, 0, 0);
        acc[i][j] = __builtin_amdgcn_mfma_f32_16x16x32_bf16(al[i], bh[j], acc[i][j], 0, 0, 0);
      }
  }

#pragma unroll
  for (int j = 0; j < 2; ++j) {
    int n = nbase + j * 16 + lr;
    float bxv = bx[n];
#pragma unroll
    for (int i = 0; i < 4; ++i)
#pragma unroll
      for (int r = 0; r < 4; ++r) {
        int m = mbase + i * 16 + (l >> 4) * 4 + r;
        out[(size_t)m * 1024 + n] = acc[i][j][r] + bxv;
      }
  }
}

// Persistent recurrence, dual-chain. 128 WGs x 512 thr (8 waves).
// WG (p, nb): chain A = row-group mbA=2p, chain B = mbB=2p+1; cols [nb*16,+16).
// Wave q owns K-slice [q*128,+128); Wh frags (shared by A,B) in registers.
// Protocol identical to R8 per chain: gate = 8 producer flags >= t; h stores
// drained (by the NEXT gate's vmcnt(0) poll) before the flag publish; a WG
// writes h_t only after all its waves' gates passed -> plane reuse race-free.
__global__ __launch_bounds__(512, 2) void rnn_persistent(
    const unsigned short* __restrict__ whh,  // [1024][1024]
    const unsigned short* __restrict__ whl,
    unsigned short* __restrict__ hb,         // [2 parity][2 hi/lo][BH]
    float* __restrict__ out,                 // [512][BH] (xproj in, h out)
    uint* __restrict__ flags)                // [4][64]
{
  __shared__ float lds[8 * 32 * 17];         // 17408 B, stride-17 pad
  const int wg = blockIdx.x;                 // 0..127
  const int p  = wg & 1;                     // pair index
  const int nb = wg >> 1;                    // 0..63
  const int mbA = 2 * p, mbB = 2 * p + 1;
  const int tid = threadIdx.x;
  const int q = tid >> 6;                    // k-slice 0..7
  const int l = tid & 63;
  const int lr = l & 15, lk = (l >> 4) * 8;
  const int kbase = q * 128 + lk;
  const int row0 = (l >> 4) * 4;

  // Wh fragments (shared by both chains): 8 frags = 32 VGPR.
  const unsigned short* bph = whh + (size_t)(nb * 16 + lr) * 1024 + kbase;
  const unsigned short* bpl = whl + (size_t)(nb * 16 + lr) * 1024 + kbase;
  bf16x8 vBh[4], vBl[4];
#pragma unroll
  for (int kb = 0; kb < 4; ++kb) {
    vBh[kb] = *reinterpret_cast<const bf16x8*>(bph + kb * 32);
    vBl[kb] = *reinterpret_cast<const bf16x8*>(bpl + kb * 32);
  }

  const size_t aoffA = (size_t)(mbA * 32 + lr) * 1024 + kbase;
  const size_t aoffB = (size_t)(mbB * 32 + lr) * 1024 + kbase;
  const int em = tid >> 4, en = tid & 15;    // 32 x 16 epilogue map
  const size_t eidxA = (size_t)(mbA * 32 + em) * 1024 + nb * 16 + en;
  const size_t eidxB = (size_t)(mbB * 32 + em) * 1024 + nb * 16 + en;
  const uint* gateA = flags + (mbA << 6) + (q << 3) + (l & 7);
  const uint* gateB = flags + (mbB << 6) + (q << 3) + (l & 7);
  uint* myA = flags + (mbA << 6) + nb;
  uint* myB = flags + (mbB << 6) + nb;

  // MFMA+LDS-reduce for one chain step; returns h = tanh(sum + xpv).
  auto chain_mm = [&](const size_t aoff, int t, float xpv) -> float {
    const unsigned short* ah = hb + (size_t)(((t - 1) & 1) * 2) * BH + aoff;
    const unsigned short* al = ah + BH;
    bf16x8 vA0h[4], vA0l[4], vA1h[4], vA1l[4];
#pragma unroll
    for (int kb = 0; kb < 4; ++kb) {
      const int ko = kb * 32;
      ldg16_sc(vA0h[kb], ah + ko);
      ldg16_sc(vA0l[kb], al + ko);
      ldg16_sc(vA1h[kb], ah + 16 * 1024 + ko);
      ldg16_sc(vA1l[kb], al + 16 * 1024 + ko);
    }
    asm volatile("s_waitcnt vmcnt(0)" ::: "memory");
    __builtin_amdgcn_sched_barrier(0);       // rule #18

    f32x4 a0 = {0.f, 0.f, 0.f, 0.f};
    f32x4 a1 = {0.f, 0.f, 0.f, 0.f};
#pragma unroll
    for (int kb = 0; kb < 4; ++kb) {
      a0 = __builtin_amdgcn_mfma_f32_16x16x32_bf16(vA0h[kb], vBh[kb], a0, 0, 0, 0);
      a1 = __builtin_amdgcn_mfma_f32_16x16x32_bf16(vA1h[kb], vBh[kb], a1, 0, 0, 0);
      a0 = __builtin_amdgcn_mfma_f32_16x16x32_bf16(vA0h[kb], vBl[kb], a0, 0, 0, 0);
      a1 = __builtin_amdgcn_mfma_f32_16x16x32_bf16(vA1h[kb], vBl[kb], a1, 0, 0, 0);
      a0 = __builtin_amdgcn_mfma_f32_16x16x32_bf16(vA0l[kb], vBh[kb], a0, 0, 0, 0);
      a1 = __builtin_amdgcn_mfma_f32_16x16x32_bf16(vA1l[kb], vBh[kb], a1, 0, 0, 0);
    }
    // C/D: col = lane&15, row = (lane>>4)*4 + r.
#pragma unroll
    for (int r = 0; r < 4; ++r) {
      lds[q * 544 + (row0 + r) * 17 + lr]      = a0[r];
      lds[q * 544 + (16 + row0 + r) * 17 + lr] = a1[r];
    }
    __syncthreads();
    float s = 0.f;
#pragma unroll
    for (int qq = 0; qq < 8; ++qq) s += lds[qq * 544 + em * 17 + en];
    return fast_tanh(s + xpv);
  };

  auto store_h = [&](int t, size_t eidx, float h) {
    unsigned short hhi = f2bf(h);
    unsigned short hlo = f2bf(h - bf2f(hhi));
    unsigned short* hcur = hb + (size_t)((t & 1) * 2) * BH;
    stg2_sc(hcur + eidx, (uint)hhi);
    stg2_sc(hcur + BH + eidx, (uint)hlo);
  };

  // Gate poll: all 8 producer flags >= tgt; vmcnt(0) per round doubles as
  // the drain for this wave's previously-issued h stores. Bounded escape.
  auto gate = [&](const uint* gp, uint tgt) {
    for (uint spin = 0; spin < (1u << 20); ++spin) {
      uint f = ld4w_sc(gp);
      if (__all((int)(f >= tgt))) break;
      __builtin_amdgcn_s_sleep(1);
    }
    __builtin_amdgcn_sched_barrier(0);
  };

  // ---- t = 0: h_0 = tanh(xp_0), both chains; explicit drain + flags. ----
  {
    float hA = fast_tanh(out[eidxA]);
    float hB = fast_tanh(out[eidxB]);
    store_h(0, eidxA, hA);
    store_h(0, eidxB, hB);
    out[eidxA] = hA;
    out[eidxB] = hB;
    asm volatile("s_waitcnt vmcnt(0)" ::: "memory");
    __syncthreads();
    if (tid == 0) { stg4_sc(myA, 1u); stg4_sc(myB, 1u); }
  }

  for (int t = 1; t < L_SEQ; ++t) {
    float* xpt = out + (size_t)t * BH;
    const float xpvA = xpt[eidxA];           // prefetch; overlaps gateA
    const float xpvB = xpt[eidxB];

    // ---- chain A segment ----
    gate(gateA, (uint)t);                    // round 1 drains hB(t-1) stores
    __syncthreads();                         // all waves drained + gated
    if (tid == 0) stg4_sc(myB, (uint)t);     // publish flagB(t-1)
    float hA = chain_mm(aoffA, t, xpvA);
    store_h(t, eidxA, hA);                   // issue only; drained by gateB

    // ---- chain B segment ----
    gate(gateB, (uint)t);                    // round 1 drains hA(t) stores
    __syncthreads();
    if (tid == 0) stg4_sc(myA, (uint)(t + 1));  // publish flagA(t)
    float hB = chain_mm(aoffB, t, xpvB);
    store_h(t, eidxB, hB);                   // drained by next gateA

    // Off the critical path: fp32 h to d_out (plain cached stores).
    xpt[eidxA] = hA;
    xpt[eidxB] = hB;
  }
}

extern "C" void kernel_launch(void* const* d_in, const int* in_sizes, int n_in,
                              void* d_out, int out_size, void* d_ws, size_t ws_size,
                              hipStream_t stream) {
  const float* x  = (const float*)d_in[0];   // [512][128][512]
  const float* Wx = (const float*)d_in[1];   // [1024][512]
  const float* bx = (const float*)d_in[2];   // [1024]
  const float* Wh = (const float*)d_in[3];   // [1024][1024]
  float* out = (float*)d_out;                // [512][128][1024]
  unsigned short* ws = (unsigned short*)d_ws;

  unsigned short* whh = ws + WS_WHH;
  unsigned short* whl = ws + WS_WHL;
  unsigned short* wxh = ws + WS_WXH;
  unsigned short* wxl = ws + WS_WXL;
  unsigned short* hb  = ws + WS_HB;          // [2][2][BH]
  uint* flags         = (uint*)(ws + WS_CNT);

  split_kernel<<<dim3(2048), dim3(256), 0, stream>>>(Wh, Wx, ws, flags);
  xproj_kernel<<<dim3(8192), dim3(256), 0, stream>>>(x, wxh, wxl, bx, out);
  rnn_persistent<<<dim3(128), dim3(512), 0, stream>>>(whh, whl, hb, out, flags);
}

// Round 11
// 4149.972 us; speedup vs baseline: 1.3911x; 1.3911x over previous
//
#include <hip/hip_runtime.h>
#include <math.h>

// RNN: L=512, B=128, D=512, H=1024, fp32 in/out.
//   xproj = x @ Wx^T + bx -> d_out;  h_t = tanh(xp_t + h_{t-1} @ Wh^T) in place.
// Precision: split-bf16 (hi+lo), 3 MFMAs per product => ~fp32 accuracy.
// Round 11: POD RESTRUCTURE + TAG-FUSED EXCHANGE.
//  - 8 independent pods (16 batch rows) x 16 col-WGs (64 cols) = 128 WGs.
//    Read amplification 64x -> 16x (R8 moved 32 MB/step through L3).
//  - h stored as 8B {payload=hi|lo, tag=t+1} via ONE global_store_dwordx2
//    sc0sc1 (single 8B transaction => payload+tag atomic). Consumers poll
//    their A-burst and check embedded tags: gate hop + store-drain hop +
//    flag hop collapse into ONE L3 round trip. Max skew = 1 step (a WG
//    passes its poll only after ALL its siblings stored, since its A spans
//    all 16 sibling tiles), so tag==t disambiguates the 2 planes.
//  - A staged to 64KB LDS; waves k-split 8; B register-resident (128 VGPR);
//    LDS partial reduce; 3 __syncthreads/step; no fences/atomics/flags.
// hbt (2MB) aliases wxh/wxl (dead after xproj) -> ws usage 6.3MB (< R8's 7.3).

#define L_SEQ 512
#define B_SZ  128
#define H_SZ  1024
#define BH    (B_SZ * H_SZ)   // 131072

typedef __bf16 bf16x8 __attribute__((ext_vector_type(8)));
typedef float  f32x4  __attribute__((ext_vector_type(4)));
typedef unsigned int uint;
typedef uint u32x4 __attribute__((ext_vector_type(4)));
typedef uint u32x2 __attribute__((ext_vector_type(2)));
typedef unsigned short ushort;

union V8 { bf16x8 b; ushort u[8]; };

__device__ __forceinline__ ushort f2bf(float f) {
  uint u = __float_as_uint(f);
  u += 0x7FFFu + ((u >> 16) & 1u);   // round-to-nearest-even
  return (ushort)(u >> 16);
}
__device__ __forceinline__ float bf2f(ushort s) {
  return __uint_as_float(((uint)s) << 16);
}

// tanh(x) = 1 - 2/(e^{2x}+1); v_exp_f32(2^x) + v_rcp_f32. Saturates right.
__device__ __forceinline__ float fast_tanh(float x) {
  float e;
  asm("v_exp_f32 %0, %1" : "=v"(e) : "v"(x * 2.885390081777927f));
  float r;
  asm("v_rcp_f32 %0, %1" : "=v"(r) : "v"(e + 1.0f));
  return 1.0f - 2.0f * r;
}

// Agent-scope (sc0 sc1): bypass L1+L2, coherent at L3. PROVEN (R8).
__device__ __forceinline__ void ldg16_sc(u32x4& d, const uint* p) {
  asm volatile("global_load_dwordx4 %0, %1, off sc0 sc1"
               : "=v"(d) : "v"(p) : "memory");
}
__device__ __forceinline__ void stg8_sc(uint* p, u32x2 v) {
  asm volatile("global_store_dwordx2 %0, %1, off sc0 sc1"
               :: "v"(p), "v"(v) : "memory");
}

// ---- d_ws layout (ushort elements) ----
#define WS_WHH 0            // [1024][1024]
#define WS_WHL 1048576      // [1024][1024]
#define WS_WXH 2097152      // [1024][512] -- after xproj, reused as hbt
#define WS_WXL 2621440      // [1024][512]
// hbt = (uint2-style)[2 planes][BH] 8B units at byte offset 4194304 (=WS_WXH*2)

// Split fp32 weights into bf16 hi + lo(residual).
__global__ void split_kernel(const float* __restrict__ Wh,
                             const float* __restrict__ Wx,
                             ushort* __restrict__ ws) {
  const int total = 1048576 + 524288;
  for (int i = blockIdx.x * blockDim.x + threadIdx.x; i < total;
       i += gridDim.x * blockDim.x) {
    const float* src; ushort *dh, *dl; int j;
    if (i < 1048576) { src = Wh; dh = ws + WS_WHH; dl = ws + WS_WHL; j = i; }
    else             { src = Wx; dh = ws + WS_WXH; dl = ws + WS_WXL; j = i - 1048576; }
    float v = src[j];
    ushort h = f2bf(v);
    dh[j] = h;
    dl[j] = f2bf(v - bf2f(h));
  }
}

// xproj: out[m][n] = sum_d x[m][d]*Wx[n][d] + bx[n]  (unchanged)
__global__ __launch_bounds__(256) void xproj_kernel(
    const float* __restrict__ x,             // [65536][512]
    const ushort* __restrict__ wxh,          // [1024][512]
    const ushort* __restrict__ wxl,
    const float* __restrict__ bx,            // [1024]
    float* __restrict__ out)                 // [65536][1024]
{
  const int bid = blockIdx.x;
  const int bn = bid & 15;
  const int bm = bid >> 4;
  const int tid = threadIdx.x;
  const int w = tid >> 6, l = tid & 63;
  const int wm = w & 1, wn = w >> 1;
  const int lr = l & 15, lk = (l >> 4) * 8;
  const int mbase = bm * 128 + wm * 64;
  const int nbase = bn * 64 + wn * 32;

  f32x4 acc[4][2] = {};

  for (int k0 = 0; k0 < 512; k0 += 32) {
    bf16x8 ah[4], al[4], bh[2], bl[2];
#pragma unroll
    for (int i = 0; i < 4; ++i) {
      const float* ap = x + (size_t)(mbase + i * 16 + lr) * 512 + k0 + lk;
      float4 v0 = *reinterpret_cast<const float4*>(ap);
      float4 v1 = *reinterpret_cast<const float4*>(ap + 4);
      float vv[8] = {v0.x, v0.y, v0.z, v0.w, v1.x, v1.y, v1.z, v1.w};
      V8 hh, ll;
#pragma unroll
      for (int e = 0; e < 8; ++e) {
        ushort hb = f2bf(vv[e]);
        hh.u[e] = hb;
        ll.u[e] = f2bf(vv[e] - bf2f(hb));
      }
      ah[i] = hh.b; al[i] = ll.b;
    }
#pragma unroll
    for (int j = 0; j < 2; ++j) {
      size_t boff = (size_t)(nbase + j * 16 + lr) * 512 + k0 + lk;
      bh[j] = *reinterpret_cast<const bf16x8*>(wxh + boff);
      bl[j] = *reinterpret_cast<const bf16x8*>(wxl + boff);
    }
#pragma unroll
    for (int i = 0; i < 4; ++i)
#pragma unroll
      for (int j = 0; j < 2; ++j) {
        acc[i][j] = __builtin_amdgcn_mfma_f32_16x16x32_bf16(ah[i], bh[j], acc[i][j], 0, 0, 0);
        acc[i][j] = __builtin_amdgcn_mfma_f32_16x16x32_bf16(ah[i], bl[j], acc[i][j], 0, 0, 0);
        acc[i][j] = __builtin_amdgcn_mfma_f32_16x16x32_bf16(al[i], bh[j], acc[i][j], 0, 0, 0);
      }
  }

#pragma unroll
  for (int j = 0; j < 2; ++j) {
    int n = nbase + j * 16 + lr;
    float bxv = bx[n];
#pragma unroll
    for (int i = 0; i < 4; ++i)
#pragma unroll
      for (int r = 0; r < 4; ++r) {
        int m = mbase + i * 16 + (l >> 4) * 4 + r;
        out[(size_t)m * 1024 + n] = acc[i][j][r] + bxv;
      }
  }
}

// Persistent recurrence. 128 WGs x 512 thr (8 waves). WG (g = bid&7, c = bid>>3):
// output tile rows [g*16,+16) x cols [c*64,+64). Pod g = 16 WGs, fully closed.
// Wave w: K-slice [w*128,+128); B (Wh cols slice) register-resident all steps.
// Per step: tag-poll A (16 dwordx4/thread, 1 L3 hop) -> unpack to LDS ->
// sync -> ds_read A-frags -> sync -> MFMA (x3 split) -> LDS partials ->
// sync -> reduce + tanh -> tagged 8B h-store + fp32 out store.
__global__ __launch_bounds__(512, 2) void rnn_persistent(
    const ushort* __restrict__ whh,  // [1024][1024]
    const ushort* __restrict__ whl,
    uint* __restrict__ hbt,          // [2 planes][BH] 8B units {payload, tag}
    float* __restrict__ out)         // [512][BH] (xproj in, h out)
{
  __shared__ uint smraw[16384];      // 64 KB
  ushort* lds_hi = (ushort*)smraw;           // [2048 units][8] bf16 hi
  ushort* lds_lo = lds_hi + 16384;           // same, lo
  float*  part   = (float*)smraw;            // alias (phase-disjoint)

  const int wg = blockIdx.x;                 // 0..127
  const int g  = wg & 7;                     // pod / row-group
  const int c  = wg >> 3;                    // col-WG 0..15
  const int tid = threadIdx.x;
  const int w = tid >> 6, l = tid & 63;
  const int lr = l & 15, lq = l >> 4;

  // ---- B preload: 4 col-tiles x 4 k-chunks, slice k in [w*128,+128). ----
  bf16x8 vBh[4][4], vBl[4][4];
#pragma unroll
  for (int ct = 0; ct < 4; ++ct)
#pragma unroll
    for (int ck = 0; ck < 4; ++ck) {
      size_t a = (size_t)(c * 64 + ct * 16 + lr) * 1024 + w * 128 + ck * 32 + lq * 8;
      vBh[ct][ck] = *reinterpret_cast<const bf16x8*>(whh + a);
      vBl[ct][ck] = *reinterpret_cast<const bf16x8*>(whl + a);
    }

  // Epilogue mapping: 2 output elems per thread over the 16x64 tile.
  const int e0 = tid * 2;
  const int row0 = e0 >> 6, cw0 = e0 & 63;       // elem 0
  const int row1 = (e0 + 1) >> 6, cw1 = (e0 + 1) & 63;
  const size_t oidx0 = (size_t)(g * 16 + row0) * 1024 + c * 64 + cw0;
  const size_t oidx1 = (size_t)(g * 16 + row1) * 1024 + c * 64 + cw1;

  // A-poll: this wave covers local elems [w*2048,+2048) of the 16x1024 slice;
  // global 8B-unit index = g*16384 + local.
  const uint* pollbase[2];
  pollbase[0] = hbt + (((size_t)g * 16384 + w * 2048 + l * 2) << 1);          // plane 0
  pollbase[1] = hbt + (((size_t)BH + g * 16384 + w * 2048 + l * 2) << 1);     // plane 1

  // ---- t = 0: h_0 = tanh(xp_0); tagged store (tag=1) into plane 0. ----
  {
    float h0 = fast_tanh(out[oidx0]);
    float h1 = fast_tanh(out[oidx1]);
    out[oidx0] = h0;
    out[oidx1] = h1;
    ushort hh0 = f2bf(h0), hh1 = f2bf(h1);
    u32x2 v0, v1;
    v0[0] = ((uint)hh0 << 16) | (uint)f2bf(h0 - bf2f(hh0)); v0[1] = 1u;
    v1[0] = ((uint)hh1 << 16) | (uint)f2bf(h1 - bf2f(hh1)); v1[1] = 1u;
    stg8_sc(hbt + (oidx0 << 1), v0);
    stg8_sc(hbt + (oidx1 << 1), v1);
  }

  for (int t = 1; t < L_SEQ; ++t) {
    float* xpt = out + (size_t)t * BH;
    const float xpv0 = xpt[oidx0];           // plain cached; overlaps poll
    const float xpv1 = xpt[oidx1];

    // ---- Tag-fused poll: ONE L3 hop when data has arrived. ----
    const uint* pb = pollbase[(t - 1) & 1];
    const uint tg = (uint)t;
    u32x4 d[16];
    for (uint spin = 0; spin < (1u << 20); ++spin) {
      #pragma unroll
      for (int i = 0; i < 16; ++i) ldg16_sc(d[i], pb + (i << 8));  // +i*128 units
      asm volatile("s_waitcnt vmcnt(0)" ::: "memory");
      __builtin_amdgcn_sched_barrier(0);     // rule #18
      bool ok = true;
      #pragma unroll
      for (int i = 0; i < 16; ++i) ok = ok && (d[i][1] == tg) && (d[i][3] == tg);
      if (__all((int)ok)) break;
      __builtin_amdgcn_s_sleep(1);
    }
    __builtin_amdgcn_sched_barrier(0);

    // ---- Stage to LDS: per i, 2 elems (same row, k even pair). ----
    #pragma unroll
    for (int i = 0; i < 16; ++i) {
      const int e = w * 2048 + i * 128 + l * 2;    // local elem index
      const int row = e >> 10, k = e & 1023;
      const int u = ((k >> 3) << 4) + row;         // LDS unit
      const int pos = k & 7;                       // even
      uint hip = (d[i][0] >> 16) | (d[i][2] & 0xFFFF0000u);
      uint lop = (d[i][0] & 0xFFFFu) | (d[i][2] << 16);
      *reinterpret_cast<uint*>(lds_hi + u * 8 + pos) = hip;
      *reinterpret_cast<uint*>(lds_lo + u * 8 + pos) = lop;
    }
    __syncthreads();                         // A staged

    // ---- A-frags (this wave's k-slice) from LDS into regs. ----
    bf16x8 vAh[4], vAl[4];
    #pragma unroll
    for (int ck = 0; ck < 4; ++ck) {
      const int u = ((w * 16 + ck * 4 + lq) << 4) + lr;
      vAh[ck] = *reinterpret_cast<const bf16x8*>(lds_hi + u * 8);
      vAl[ck] = *reinterpret_cast<const bf16x8*>(lds_lo + u * 8);
    }
    __syncthreads();                         // all A-reads done (LDS reused)

    // ---- MFMA: 4 col-tiles x 4 chunks x 3 (split). ----
    f32x4 acc[4] = {};
    #pragma unroll
    for (int ct = 0; ct < 4; ++ct)
      #pragma unroll
      for (int ck = 0; ck < 4; ++ck) {
        acc[ct] = __builtin_amdgcn_mfma_f32_16x16x32_bf16(vAh[ck], vBh[ct][ck], acc[ct], 0, 0, 0);
        acc[ct] = __builtin_amdgcn_mfma_f32_16x16x32_bf16(vAh[ck], vBl[ct][ck], acc[ct], 0, 0, 0);
        acc[ct] = __builtin_amdgcn_mfma_f32_16x16x32_bf16(vAl[ck], vBh[ct][ck], acc[ct], 0, 0, 0);
      }

    // ---- Partials -> LDS. C/D: col = ct*16+(l&15), row = lq*4+r. ----
    #pragma unroll
    for (int ct = 0; ct < 4; ++ct)
      #pragma unroll
      for (int r = 0; r < 4; ++r)
        part[w * 1088 + (ct * 16 + lr) * 17 + lq * 4 + r] = acc[ct][r];
    __syncthreads();                         // partials complete

    // ---- Reduce 8 k-slices, tanh, tagged h-store + fp32 out. ----
    float s0 = 0.f, s1 = 0.f;
    #pragma unroll
    for (int q = 0; q < 8; ++q) {
      s0 += part[q * 1088 + cw0 * 17 + row0];
      s1 += part[q * 1088 + cw1 * 17 + row1];
    }
    float h0 = fast_tanh(s0 + xpv0);
    float h1 = fast_tanh(s1 + xpv1);
    ushort hh0 = f2bf(h0), hh1 = f2bf(h1);
    u32x2 v0, v1;
    v0[0] = ((uint)hh0 << 16) | (uint)f2bf(h0 - bf2f(hh0)); v0[1] = tg + 1u;
    v1[0] = ((uint)hh1 << 16) | (uint)f2bf(h1 - bf2f(hh1)); v1[1] = tg + 1u;
    uint* planew = hbt + ((size_t)(t & 1) * BH << 1);
    stg8_sc(planew + (oidx0 << 1), v0);
    stg8_sc(planew + (oidx1 << 1), v1);
    xpt[oidx0] = h0;                         // off the exchange path
    xpt[oidx1] = h1;
  }
}

extern "C" void kernel_launch(void* const* d_in, const int* in_sizes, int n_in,
                              void* d_out, int out_size, void* d_ws, size_t ws_size,
                              hipStream_t stream) {
  const float* x  = (const float*)d_in[0];   // [512][128][512]
  const float* Wx = (const float*)d_in[1];   // [1024][512]
  const float* bx = (const float*)d_in[2];   // [1024]
  const float* Wh = (const float*)d_in[3];   // [1024][1024]
  float* out = (float*)d_out;                // [512][128][1024]
  ushort* ws = (ushort*)d_ws;

  ushort* whh = ws + WS_WHH;
  ushort* whl = ws + WS_WHL;
  ushort* wxh = ws + WS_WXH;
  ushort* wxl = ws + WS_WXL;
  uint*   hbt = (uint*)(ws + WS_WXH);        // aliases wx region (dead post-xproj)

  split_kernel<<<dim3(2048), dim3(256), 0, stream>>>(Wh, Wx, ws);
  xproj_kernel<<<dim3(8192), dim3(256), 0, stream>>>(x, wxh, wxl, bx, out);
  rnn_persistent<<<dim3(128), dim3(512), 0, stream>>>(whh, whl, hbt, out);
}